// Round 6
// baseline (280.646 us; speedup 1.0000x reference)
//
#include <hip/hip_runtime.h>
#include <stdint.h>

#define NB 2
#define NS 2048
#define NHID 1024
#define NHEADS 4
#define DHEAD 256
#define NP 128            // DHEAD/2
#define QK_SCALE 0.0625f  // HD^-0.5

typedef unsigned short ushort_t;
typedef __bf16 bf16x8 __attribute__((ext_vector_type(8)));
typedef float floatx4 __attribute__((ext_vector_type(4)));
typedef short shortx8 __attribute__((ext_vector_type(8)));
typedef unsigned short ushortx4 __attribute__((ext_vector_type(4)));
typedef unsigned short ushortx8 __attribute__((ext_vector_type(8)));

__device__ __forceinline__ float bf2f(ushort_t u) {
    unsigned int x = ((unsigned int)u) << 16;
    return __builtin_bit_cast(float, x);
}
__device__ __forceinline__ ushort_t f2bf(float f) {
    unsigned int u = __builtin_bit_cast(unsigned int, f);
    u += 0x7fff + ((u >> 16) & 1);   // RNE
    return (ushort_t)(u >> 16);
}

__device__ __forceinline__ floatx4 mfma16(bf16x8 a, bf16x8 b, floatx4 c) {
    return __builtin_amdgcn_mfma_f32_16x16x32_bf16(a, b, c, 0, 0, 0);
}

__device__ __forceinline__ void gload_lds16(const void* g, void* l) {
    __builtin_amdgcn_global_load_lds(
        (const __attribute__((address_space(1))) void*)g,
        (__attribute__((address_space(3))) void*)l, 16, 0, 0);
}

// ---------------- fused cast fp32 -> bf16 for hidden + Wqkv + Wo ----------------
#define N4_H (4096 * 1024 / 4)
#define N4_WQ (3072 * 1024 / 4)
#define N4_WO (1024 * 1024 / 4)
__global__ __launch_bounds__(256) void cast3_kernel(const float* __restrict__ inH,
                                                    const float* __restrict__ inWq,
                                                    const float* __restrict__ inWo,
                                                    ushort_t* __restrict__ out) {
    int i = blockIdx.x * 256 + threadIdx.x;
    const float* src;
    int j = i;
    if (i < N4_H) {
        src = inH;
    } else if (i < N4_H + N4_WQ) {
        src = inWq; j = i - N4_H;
    } else {
        src = inWo; j = i - (N4_H + N4_WQ);
    }
    float4 v = ((const float4*)src)[j];
    ushortx4 o = { f2bf(v.x), f2bf(v.y), f2bf(v.z), f2bf(v.w) };
    ((ushortx4*)out)[i] = o;
}

// ---------------- GEMM, Bt form, fp32 out, split-K x2 (blockIdx.z) ----------------
__global__ __launch_bounds__(256) void gemm_bt_f32s(const ushort_t* __restrict__ A,
                                                    const ushort_t* __restrict__ Bt,
                                                    float* __restrict__ C0,
                                                    float* __restrict__ C1,
                                                    int M, int N, int K) {
    __shared__ ushort_t sA[128 * 32];
    __shared__ ushort_t sB[128 * 32];
    const int t = threadIdx.x;
    const int m0 = blockIdx.y * 128;
    const int n0 = blockIdx.x * 128;
    const int kz = blockIdx.z;
    float* Cout = kz ? C1 : C0;
    const int kbeg = kz * (K / 2), kend = kbeg + K / 2;
    const int w = t >> 6, l = t & 63;
    const int wm = (w >> 1) * 64, wn = (w & 1) * 64;
    const int lc = l & 15, lq = l >> 4;

    floatx4 acc[4][4];
#pragma unroll
    for (int i = 0; i < 4; i++)
#pragma unroll
        for (int j = 0; j < 4; j++) acc[i][j] = (floatx4){0.f, 0.f, 0.f, 0.f};

    const int r0 = t >> 2, c8 = (t & 3) * 8;
    const ushort_t* Ag0 = A + (size_t)(m0 + r0) * K + c8;
    const ushort_t* Ag1 = A + (size_t)(m0 + r0 + 64) * K + c8;
    const ushort_t* Bg0 = Bt + (size_t)(n0 + r0) * K + c8;
    const ushort_t* Bg1 = Bt + (size_t)(n0 + r0 + 64) * K + c8;
    ushort_t* lA0 = &sA[(size_t)t * 8];
    ushort_t* lA1 = &sA[(size_t)(t + 256) * 8];
    ushort_t* lB0 = &sB[(size_t)t * 8];
    ushort_t* lB1 = &sB[(size_t)(t + 256) * 8];

    for (int kk = kbeg; kk < kend; kk += 32) {
        __syncthreads();
        gload_lds16(Ag0 + kk, lA0);
        gload_lds16(Ag1 + kk, lA1);
        gload_lds16(Bg0 + kk, lB0);
        gload_lds16(Bg1 + kk, lB1);
        __syncthreads();
        bf16x8 af[4], bfv[4];
#pragma unroll
        for (int i = 0; i < 4; i++)
            af[i] = *(const bf16x8*)&sA[(wm + i * 16 + lc) * 32 + lq * 8];
#pragma unroll
        for (int j = 0; j < 4; j++)
            bfv[j] = *(const bf16x8*)&sB[(wn + j * 16 + lc) * 32 + lq * 8];
#pragma unroll
        for (int i = 0; i < 4; i++)
#pragma unroll
            for (int j = 0; j < 4; j++)
                acc[i][j] = mfma16(af[i], bfv[j], acc[i][j]);
    }

#pragma unroll
    for (int i = 0; i < 4; i++) {
        int row = m0 + wm + i * 16 + lq * 4;
#pragma unroll
        for (int j = 0; j < 4; j++) {
            int col = n0 + wn + j * 16 + lc;
#pragma unroll
            for (int r = 0; r < 4; r++)
                Cout[(size_t)(row + r) * N + col] = acc[i][j][r];
        }
    }
}

// ---------------- add two fp32 partials -> d_out ----------------
__global__ __launch_bounds__(256) void add_f32(const float* __restrict__ a,
                                               const float* __restrict__ b,
                                               float* __restrict__ o, int n4) {
    int i = blockIdx.x * 256 + threadIdx.x;
    if (i < n4) {
        float4 x = ((const float4*)a)[i];
        float4 y = ((const float4*)b)[i];
        float4 z = { x.x + y.x, x.y + y.y, x.z + y.z, x.w + y.w };
        ((float4*)o)[i] = z;
    }
}

// ---------------- QKV GEMM with fused RoPE + split + V-transpose epilogue ----
__global__ __launch_bounds__(256) void gemm_qkv(const ushort_t* __restrict__ A,
                                                const ushort_t* __restrict__ Bt,
                                                const float* __restrict__ fre,
                                                const float* __restrict__ fim,
                                                ushort_t* __restrict__ Q,
                                                ushort_t* __restrict__ Kk,
                                                ushort_t* __restrict__ Vt) {
    const int M_K = 1024;
    __shared__ ushort_t sA[128 * 32];
    __shared__ ushort_t sB[128 * 32];
    const int t = threadIdx.x;
    const int m0 = blockIdx.y * 128;
    const int n0 = blockIdx.x * 128;
    const int w = t >> 6, l = t & 63;
    const int wm = (w >> 1) * 64, wn = (w & 1) * 64;
    const int lc = l & 15, lq = l >> 4;

    floatx4 acc[4][4];
#pragma unroll
    for (int i = 0; i < 4; i++)
#pragma unroll
        for (int j = 0; j < 4; j++) acc[i][j] = (floatx4){0.f, 0.f, 0.f, 0.f};

    const int r0 = t >> 2, c8 = (t & 3) * 8;
    const ushort_t* Ag0 = A + (size_t)(m0 + r0) * M_K + c8;
    const ushort_t* Ag1 = A + (size_t)(m0 + r0 + 64) * M_K + c8;
    const ushort_t* Bg0 = Bt + (size_t)(n0 + r0) * M_K + c8;
    const ushort_t* Bg1 = Bt + (size_t)(n0 + r0 + 64) * M_K + c8;
    ushort_t* lA0 = &sA[(size_t)t * 8];
    ushort_t* lA1 = &sA[(size_t)(t + 256) * 8];
    ushort_t* lB0 = &sB[(size_t)t * 8];
    ushort_t* lB1 = &sB[(size_t)(t + 256) * 8];

    for (int kk = 0; kk < M_K; kk += 32) {
        __syncthreads();
        gload_lds16(Ag0 + kk, lA0);
        gload_lds16(Ag1 + kk, lA1);
        gload_lds16(Bg0 + kk, lB0);
        gload_lds16(Bg1 + kk, lB1);
        __syncthreads();
        bf16x8 af[4], bfv[4];
#pragma unroll
        for (int i = 0; i < 4; i++)
            af[i] = *(const bf16x8*)&sA[(wm + i * 16 + lc) * 32 + lq * 8];
#pragma unroll
        for (int j = 0; j < 4; j++)
            bfv[j] = *(const bf16x8*)&sB[(wn + j * 16 + lc) * 32 + lq * 8];
#pragma unroll
        for (int i = 0; i < 4; i++)
#pragma unroll
            for (int j = 0; j < 4; j++)
                acc[i][j] = mfma16(af[i], bfv[j], acc[i][j]);
    }

    // ---- fused epilogue ----
    const int sect = n0 >> 10;                    // uniform per block
#pragma unroll
    for (int i = 0; i < 4; i++) {
        int row = m0 + wm + i * 16 + lq * 4;      // + r
        int b = row >> 11;                        // uniform per block
        int srow = row & 2047;
#pragma unroll
        for (int j = 0; j < 4; j++) {
            int col = n0 + wn + j * 16 + lc;
            int d = col & 255;
            int h = (col >> 8) & 3;
            int bh = b * NHEADS + h;
            if (sect == 2) {
                ushortx4 pack = { f2bf(acc[i][j][0]), f2bf(acc[i][j][1]),
                                  f2bf(acc[i][j][2]), f2bf(acc[i][j][3]) };
                *(ushortx4*)&Vt[((size_t)bh * 256 + d) * NS + srow] = pack;
            } else {
                int p = d >> 1;
                int odd = d & 1;
                ushort_t* dst = (sect == 0) ? Q : Kk;
#pragma unroll
                for (int r = 0; r < 4; r++) {
                    float v = acc[i][j][r];
                    float vp = __shfl_xor(v, 1);
                    int s = srow + r;
                    float c = fre[s * NP + p], si = fim[s * NP + p];
                    float out = odd ? (vp * si + v * c) : (v * c - vp * si);
                    if (sect == 0) out *= QK_SCALE;
                    dst[((size_t)bh * NS + s) * DHEAD + d] = f2bf(out);
                }
            }
        }
    }
}

// ---------------- flash attention v5: barrier-free, direct-global B-frags ----
// BQ=128 (4 waves x 32 q-rows), BKV=64, no-max streaming softmax, split cap 5
// (488 blocks). K and V MFMA B-fragments are 16B/lane contiguous loads straight
// from global (K row-major, Vt transposed); the 4x wave redundancy is absorbed
// by L1 (32KB/phase = exact fit). No __syncthreads anywhere; LDS only for the
// per-wave P C->A layout round-trip (18KB) -> 2 blocks/CU, free wave slip.
#define BQ3 128
#define BKV3 64
#define PPAD 72
#define CHCAP 5
#define NPART_BH 61       // sum over qt of ceil(2(qt+1)/5)
#define OPART_SPLIT 224   // partials 0..223 in region A, rest in region B

__global__ __launch_bounds__(256, 2) void flash_attn5(const ushort_t* __restrict__ Q,
                                                      const ushort_t* __restrict__ K,
                                                      const ushort_t* __restrict__ Vt,
                                                      ushort_t* __restrict__ OpA,
                                                      ushort_t* __restrict__ OpB,
                                                      float* __restrict__ ml) {
    __shared__ ushort_t sP[4][32 * PPAD];      // 18432 B, per-wave

    int rem = blockIdx.x, qt = 15, nsp;
    for (;;) {
        nsp = (2 * (qt + 1) + CHCAP - 1) / CHCAP;
        if (rem < nsp) break;
        rem -= nsp;
        qt--;
    }
    const int nch = 2 * (qt + 1);
    const int cbeg = rem * CHCAP;
    const int cend = (cbeg + CHCAP < nch) ? cbeg + CHCAP : nch;

    const int h = blockIdx.y, b = blockIdx.z;
    const int t = threadIdx.x, w = t >> 6, l = t & 63;
    const int lc = l & 15, lq = l >> 4;
    const int bh = b * NHEADS + h;
    const size_t base = (size_t)bh * NS * DHEAD;
    const int q0 = qt * BQ3;

    // Q fragments: wave w owns rows [q0+w*32, +32), two 16-row groups
    bf16x8 qf[2][8];
#pragma unroll
    for (int gq = 0; gq < 2; gq++) {
        const ushort_t* qrow = Q + base + (size_t)(q0 + w * 32 + gq * 16 + lc) * DHEAD + lq * 8;
#pragma unroll
        for (int dk = 0; dk < 8; dk++) qf[gq][dk] = *(const bf16x8*)(qrow + dk * 32);
    }

    floatx4 accO[2][16];
#pragma unroll
    for (int gq = 0; gq < 2; gq++)
#pragma unroll
        for (int j = 0; j < 16; j++) accO[gq][j] = (floatx4){0.f, 0.f, 0.f, 0.f};
    float lrun[2][4] = {{0.f, 0.f, 0.f, 0.f}, {0.f, 0.f, 0.f, 0.f}};

    for (int kc = cbeg; kc < cend; kc++) {
        const int kb = kc * BKV3;
        const ushort_t* Kc = K + base + (size_t)kb * DHEAD;   // [key][d]
        const ushort_t* Vc = Vt + base + kb;                  // [d][key]

        // S = Q K^T : B-frags direct from global (16B/lane, L1-resident)
        floatx4 sfr[2][4];
#pragma unroll
        for (int gq = 0; gq < 2; gq++)
#pragma unroll
            for (int g = 0; g < 4; g++) sfr[gq][g] = (floatx4){0.f, 0.f, 0.f, 0.f};
#pragma unroll
        for (int dk = 0; dk < 8; dk++) {
#pragma unroll
            for (int g = 0; g < 4; g++) {
                bf16x8 bk = *(const bf16x8*)(Kc + (size_t)(g * 16 + lc) * DHEAD + dk * 32 + lq * 8);
                sfr[0][g] = mfma16(qf[0][dk], bk, sfr[0][g]);
                sfr[1][g] = mfma16(qf[1][dk], bk, sfr[1][g]);
            }
        }

        // causal mask only on the two diagonal chunks
        if (kc >= nch - 2) {
#pragma unroll
            for (int gq = 0; gq < 2; gq++)
#pragma unroll
                for (int g = 0; g < 4; g++) {
                    int kg = kb + g * 16 + lc;
                    int qr = q0 + w * 32 + gq * 16 + lq * 4;
#pragma unroll
                    for (int r = 0; r < 4; r++)
                        if (kg > qr + r) sfr[gq][g][r] = -1e30f;
                }
        }

        // streaming softmax (M=0 fixed): p = exp(s); P via per-wave LDS
        ushort_t* pw = sP[w];
#pragma unroll
        for (int gq = 0; gq < 2; gq++)
#pragma unroll
            for (int g = 0; g < 4; g++)
#pragma unroll
                for (int r = 0; r < 4; r++) {
                    float p = __expf(sfr[gq][g][r]);
                    lrun[gq][r] += p;
                    pw[(gq * 16 + lq * 4 + r) * PPAD + g * 16 + lc] = f2bf(p);
                }
        bf16x8 ap[2][2];
#pragma unroll
        for (int gq = 0; gq < 2; gq++) {
            ap[gq][0] = *(const bf16x8*)&pw[(gq * 16 + lc) * PPAD + lq * 8];
            ap[gq][1] = *(const bf16x8*)&pw[(gq * 16 + lc) * PPAD + 32 + lq * 8];
        }
        // O += P V : V-frags direct from global (contiguous 16B/lane), shared by both gq
#pragma unroll
        for (int j = 0; j < 16; j++) {
            const ushort_t* vrow = Vc + (size_t)(j * 16 + lc) * NS + lq * 8;
            bf16x8 bv0 = *(const bf16x8*)vrow;
            bf16x8 bv1 = *(const bf16x8*)(vrow + 32);
            accO[0][j] = mfma16(ap[0][0], bv0, accO[0][j]);
            accO[0][j] = mfma16(ap[0][1], bv1, accO[0][j]);
            accO[1][j] = mfma16(ap[1][0], bv0, accO[1][j]);
            accO[1][j] = mfma16(ap[1][1], bv1, accO[1][j]);
        }
    }

    // ---- epilogue: unnormalized partial O (bf16) + row sums l ----
    const int pid = bh * NPART_BH + blockIdx.x;
    ushort_t* op = (pid < OPART_SPLIT) ? OpA + (size_t)pid * (128 * 256)
                                       : OpB + (size_t)(pid - OPART_SPLIT) * (128 * 256);
#pragma unroll
    for (int gq = 0; gq < 2; gq++) {
#pragma unroll
        for (int r = 0; r < 4; r++) {
            int row = w * 32 + gq * 16 + lq * 4 + r;
#pragma unroll
            for (int j = 0; j < 16; j++)
                op[row * 256 + j * 16 + lc] = f2bf(accO[gq][j][r]);
            float lv = lrun[gq][r];
#pragma unroll
            for (int off = 1; off < 16; off <<= 1) lv += __shfl_xor(lv, off);
            if (lc == 0) ml[(size_t)pid * 128 + row] = lv;
        }
    }
}

// ---------------- combine partials: fully parallel, vectorized ----------------
__global__ __launch_bounds__(256) void combine_parts2(const ushort_t* __restrict__ OpA,
                                                      const ushort_t* __restrict__ OpB,
                                                      const float* __restrict__ ml,
                                                      ushort_t* __restrict__ O) {
    const int qt = blockIdx.x >> 3, rsub = blockIdx.x & 7;
    const int h = blockIdx.y, b = blockIdx.z;
    const int bh = b * NHEADS + h;
    int bbase = 0;
    for (int q = 15; q > qt; q--) bbase += (2 * (q + 1) + CHCAP - 1) / CHCAP;
    const int nsp = (2 * (qt + 1) + CHCAP - 1) / CHCAP;
    const int pid0 = bh * NPART_BH + bbase;

    const int t = threadIdx.x;
    const int rl = t >> 4;               // 0..15 local row
    const int c0 = (t & 15) * 16;        // col base
    const int row = rsub * 16 + rl;      // row within 128-row q-tile

    float so[16];
#pragma unroll
    for (int k = 0; k < 16; k++) so[k] = 0.f;
    float sl = 0.f;

    for (int i = 0; i < nsp; i++) {
        int pid = pid0 + i;
        const ushort_t* op = (pid < OPART_SPLIT)
                                 ? OpA + (size_t)pid * (128 * 256)
                                 : OpB + (size_t)(pid - OPART_SPLIT) * (128 * 256);
        const ushort_t* p = op + row * 256 + c0;
        ushortx8 a0 = *(const ushortx8*)p;
        ushortx8 a1 = *(const ushortx8*)(p + 8);
#pragma unroll
        for (int k = 0; k < 8; k++) {
            so[k] += bf2f(a0[k]);
            so[8 + k] += bf2f(a1[k]);
        }
        sl += ml[(size_t)pid * 128 + row];
    }

    float inv = 1.f / sl;
    ushortx8 o0, o1;
#pragma unroll
    for (int k = 0; k < 8; k++) {
        o0[k] = f2bf(so[k] * inv);
        o1[k] = f2bf(so[8 + k] * inv);
    }
    int s = qt * BQ3 + row;
    ushort_t* dst = O + ((size_t)(b * NS + s) * NHEADS + h) * DHEAD + c0;
    *(ushortx8*)dst = o0;
    *(ushortx8*)(dst + 8) = o1;
}

// ---------------- launch ----------------
extern "C" void kernel_launch(void* const* d_in, const int* in_sizes, int n_in,
                              void* d_out, int out_size, void* d_ws, size_t ws_size,
                              hipStream_t stream) {
    const float* hidden = (const float*)d_in[0];
    const float* fre = (const float*)d_in[1];
    const float* fim = (const float*)d_in[2];
    // d_in[3] = mask (causal, reproduced analytically)
    const float* Wqkv = (const float*)d_in[4];
    const float* Wo = (const float*)d_in[5];

    char* ws = (char*)d_ws;
    ushort_t* hb    = (ushort_t*)(ws);                 // [0,8M)   dead after gemm_qkv
    ushort_t* wqkvb = (ushort_t*)(ws + 8388608);       // [8,14M)  dead after gemm_qkv
    ushort_t* wob   = (ushort_t*)(ws + 14680064);      // [14,16M) live till gemm2
    ushort_t* qb    = (ushort_t*)(ws + 16777216);      // [16,24M) dead after flash
    ushort_t* kb    = (ushort_t*)(ws + 25165824);      // [24,32M) dead after flash
    ushort_t* vtb   = (ushort_t*)(ws + 33554432);      // [32,40M) dead after flash
    ushort_t* OpA   = (ushort_t*)(ws);                 // [0,14M)  224 partials (over hb+wqkvb)
    ushort_t* OpB   = (ushort_t*)(ws + 41943040);      // [40M,+16.5M) 264 partials
    ushort_t* oattn = (ushort_t*)(ws + 16777216);      // over dead qb
    float*    gP0   = (float*)(ws + 25165824);         // [24,40M) over dead kb+vtb
    float*    gP1   = (float*)(ws + 41943040);         // [40,56M) over dead OpB
    float*    ml    = (float*)(ws + 60817408);         // [58M, +250K)

    cast3_kernel<<<(N4_H + N4_WQ + N4_WO) / 256, 256, 0, stream>>>(hidden, Wqkv, Wo, hb);

    gemm_qkv<<<dim3(3072 / 128, 4096 / 128), 256, 0, stream>>>(
        hb, wqkvb, fre, fim, qb, kb, vtb);

    flash_attn5<<<dim3(NPART_BH, NHEADS, NB), 256, 0, stream>>>(qb, kb, vtb, OpA, OpB, ml);
    combine_parts2<<<dim3(128, NHEADS, NB), 256, 0, stream>>>(OpA, OpB, ml, oattn);

    gemm_bt_f32s<<<dim3(1024 / 128, 4096 / 128, 2), 256, 0, stream>>>(
        oattn, wob, gP0, gP1, 4096, 1024, 1024);
    add_f32<<<4096, 256, 0, stream>>>(gP0, gP1, (float*)d_out, 4096 * 1024 / 4);
}

// Round 7
// 208.562 us; speedup vs baseline: 1.3456x; 1.3456x over previous
//
#include <hip/hip_runtime.h>
#include <stdint.h>

#define NB 2
#define NS 2048
#define NHID 1024
#define NHEADS 4
#define DHEAD 256
#define NP 128            // DHEAD/2
#define QK_SCALE 0.0625f  // HD^-0.5

typedef unsigned short ushort_t;
typedef __bf16 bf16x8 __attribute__((ext_vector_type(8)));
typedef float floatx4 __attribute__((ext_vector_type(4)));
typedef short shortx8 __attribute__((ext_vector_type(8)));
typedef unsigned short ushortx4 __attribute__((ext_vector_type(4)));
typedef unsigned short ushortx8 __attribute__((ext_vector_type(8)));

__device__ __forceinline__ float bf2f(ushort_t u) {
    unsigned int x = ((unsigned int)u) << 16;
    return __builtin_bit_cast(float, x);
}
__device__ __forceinline__ ushort_t f2bf(float f) {
    unsigned int u = __builtin_bit_cast(unsigned int, f);
    u += 0x7fff + ((u >> 16) & 1);   // RNE
    return (ushort_t)(u >> 16);
}

__device__ __forceinline__ floatx4 mfma16(bf16x8 a, bf16x8 b, floatx4 c) {
    return __builtin_amdgcn_mfma_f32_16x16x32_bf16(a, b, c, 0, 0, 0);
}

__device__ __forceinline__ void gload_lds16(const void* g, void* l) {
    __builtin_amdgcn_global_load_lds(
        (const __attribute__((address_space(1))) void*)g,
        (__attribute__((address_space(3))) void*)l, 16, 0, 0);
}

// ---------------- fused cast fp32 -> bf16 for hidden + Wqkv + Wo ----------------
#define N4_H (4096 * 1024 / 4)
#define N4_WQ (3072 * 1024 / 4)
#define N4_WO (1024 * 1024 / 4)
__global__ __launch_bounds__(256) void cast3_kernel(const float* __restrict__ inH,
                                                    const float* __restrict__ inWq,
                                                    const float* __restrict__ inWo,
                                                    ushort_t* __restrict__ out) {
    int i = blockIdx.x * 256 + threadIdx.x;
    const float* src;
    int j = i;
    if (i < N4_H) {
        src = inH;
    } else if (i < N4_H + N4_WQ) {
        src = inWq; j = i - N4_H;
    } else {
        src = inWo; j = i - (N4_H + N4_WQ);
    }
    float4 v = ((const float4*)src)[j];
    ushortx4 o = { f2bf(v.x), f2bf(v.y), f2bf(v.z), f2bf(v.w) };
    ((ushortx4*)out)[i] = o;
}

// ============ shared BK=64 GEMM machinery (rot-swizzled LDS) ============
// LDS layout: [row][64 cols], 16B chunk c of row r stored at phys (c + r) & 7.
// Staging: lane l's fixed source col-chunk is ((l&7)-(l>>3))&7; dest = t*16B + j*4KB
// (wave-uniform base + lane*16 -> DMA-legal). Reads land 2-way banked (free).

// ---------------- GEMM, Bt form, fp32 out, split-K x2 (blockIdx.z) ----------------
__global__ __launch_bounds__(256) void gemm_bt_f32s(const ushort_t* __restrict__ A,
                                                    const ushort_t* __restrict__ Bt,
                                                    float* __restrict__ C0,
                                                    float* __restrict__ C1,
                                                    int M, int N, int K) {
    __shared__ ushort_t sA[128 * 64];
    __shared__ ushort_t sB[128 * 64];
    const int t = threadIdx.x;
    const int m0 = blockIdx.y * 128;
    const int n0 = blockIdx.x * 128;
    const int kz = blockIdx.z;
    float* Cout = kz ? C1 : C0;
    const int kbeg = kz * (K / 2), kend = kbeg + K / 2;
    const int w = t >> 6, l = t & 63;
    const int wm = (w >> 1) * 64, wn = (w & 1) * 64;
    const int lc = l & 15, lq = l >> 4;

    floatx4 acc[4][4];
#pragma unroll
    for (int i = 0; i < 4; i++)
#pragma unroll
        for (int j = 0; j < 4; j++) acc[i][j] = (floatx4){0.f, 0.f, 0.f, 0.f};

    const int srow = w * 8 + (l >> 3);                    // + j*32 per issue
    const int scol = ((((l & 7) - (l >> 3)) & 7)) * 8;    // lane-fixed swizzled col
    const ushort_t* Ag = A + (size_t)(m0 + srow) * K + scol;
    const ushort_t* Bg = Bt + (size_t)(n0 + srow) * K + scol;
    ushort_t* lA = &sA[(size_t)t * 8];
    ushort_t* lB = &sB[(size_t)t * 8];

    for (int kk = kbeg; kk < kend; kk += 64) {
        __syncthreads();
#pragma unroll
        for (int j = 0; j < 4; j++) {
            gload_lds16(Ag + kk + (size_t)j * 32 * K, lA + j * 2048);
            gload_lds16(Bg + kk + (size_t)j * 32 * K, lB + j * 2048);
        }
        __syncthreads();
#pragma unroll
        for (int ks = 0; ks < 2; ks++) {
            bf16x8 af[4], bfv[4];
#pragma unroll
            for (int i = 0; i < 4; i++) {
                int R = wm + i * 16 + lc;
                af[i] = *(const bf16x8*)&sA[R * 64 + ((ks * 4 + lq + R) & 7) * 8];
            }
#pragma unroll
            for (int j = 0; j < 4; j++) {
                int R = wn + j * 16 + lc;
                bfv[j] = *(const bf16x8*)&sB[R * 64 + ((ks * 4 + lq + R) & 7) * 8];
            }
#pragma unroll
            for (int i = 0; i < 4; i++)
#pragma unroll
                for (int j = 0; j < 4; j++)
                    acc[i][j] = mfma16(af[i], bfv[j], acc[i][j]);
        }
    }

#pragma unroll
    for (int i = 0; i < 4; i++) {
        int row = m0 + wm + i * 16 + lq * 4;
#pragma unroll
        for (int j = 0; j < 4; j++) {
            int col = n0 + wn + j * 16 + lc;
#pragma unroll
            for (int r = 0; r < 4; r++)
                Cout[(size_t)(row + r) * N + col] = acc[i][j][r];
        }
    }
}

// ---------------- add two fp32 partials -> d_out ----------------
__global__ __launch_bounds__(256) void add_f32(const float* __restrict__ a,
                                               const float* __restrict__ b,
                                               float* __restrict__ o, int n4) {
    int i = blockIdx.x * 256 + threadIdx.x;
    if (i < n4) {
        float4 x = ((const float4*)a)[i];
        float4 y = ((const float4*)b)[i];
        float4 z = { x.x + y.x, x.y + y.y, x.z + y.z, x.w + y.w };
        ((float4*)o)[i] = z;
    }
}

// ---------------- QKV GEMM (BK=64, swizzled) + fused RoPE/split/V-transpose ----
__global__ __launch_bounds__(256) void gemm_qkv(const ushort_t* __restrict__ A,
                                                const ushort_t* __restrict__ Bt,
                                                const float* __restrict__ fre,
                                                const float* __restrict__ fim,
                                                ushort_t* __restrict__ Q,
                                                ushort_t* __restrict__ Kk,
                                                ushort_t* __restrict__ Vt) {
    const int M_K = 1024;
    __shared__ ushort_t sA[128 * 64];
    __shared__ ushort_t sB[128 * 64];
    const int t = threadIdx.x;
    const int m0 = blockIdx.y * 128;
    const int n0 = blockIdx.x * 128;
    const int w = t >> 6, l = t & 63;
    const int wm = (w >> 1) * 64, wn = (w & 1) * 64;
    const int lc = l & 15, lq = l >> 4;

    floatx4 acc[4][4];
#pragma unroll
    for (int i = 0; i < 4; i++)
#pragma unroll
        for (int j = 0; j < 4; j++) acc[i][j] = (floatx4){0.f, 0.f, 0.f, 0.f};

    const int srow = w * 8 + (l >> 3);
    const int scol = ((((l & 7) - (l >> 3)) & 7)) * 8;
    const ushort_t* Ag = A + (size_t)(m0 + srow) * M_K + scol;
    const ushort_t* Bg = Bt + (size_t)(n0 + srow) * M_K + scol;
    ushort_t* lA = &sA[(size_t)t * 8];
    ushort_t* lB = &sB[(size_t)t * 8];

    for (int kk = 0; kk < M_K; kk += 64) {
        __syncthreads();
#pragma unroll
        for (int j = 0; j < 4; j++) {
            gload_lds16(Ag + kk + (size_t)j * 32 * M_K, lA + j * 2048);
            gload_lds16(Bg + kk + (size_t)j * 32 * M_K, lB + j * 2048);
        }
        __syncthreads();
#pragma unroll
        for (int ks = 0; ks < 2; ks++) {
            bf16x8 af[4], bfv[4];
#pragma unroll
            for (int i = 0; i < 4; i++) {
                int R = wm + i * 16 + lc;
                af[i] = *(const bf16x8*)&sA[R * 64 + ((ks * 4 + lq + R) & 7) * 8];
            }
#pragma unroll
            for (int j = 0; j < 4; j++) {
                int R = wn + j * 16 + lc;
                bfv[j] = *(const bf16x8*)&sB[R * 64 + ((ks * 4 + lq + R) & 7) * 8];
            }
#pragma unroll
            for (int i = 0; i < 4; i++)
#pragma unroll
                for (int j = 0; j < 4; j++)
                    acc[i][j] = mfma16(af[i], bfv[j], acc[i][j]);
        }
    }

    // ---- fused epilogue ----
    const int sect = n0 >> 10;                    // uniform per block
#pragma unroll
    for (int i = 0; i < 4; i++) {
        int row = m0 + wm + i * 16 + lq * 4;      // + r
        int b = row >> 11;                        // uniform per block
        int srow2 = row & 2047;
#pragma unroll
        for (int j = 0; j < 4; j++) {
            int col = n0 + wn + j * 16 + lc;
            int d = col & 255;
            int h = (col >> 8) & 3;
            int bh = b * NHEADS + h;
            if (sect == 2) {
                ushortx4 pack = { f2bf(acc[i][j][0]), f2bf(acc[i][j][1]),
                                  f2bf(acc[i][j][2]), f2bf(acc[i][j][3]) };
                *(ushortx4*)&Vt[((size_t)bh * 256 + d) * NS + srow2] = pack;
            } else {
                int p = d >> 1;
                int odd = d & 1;
                ushort_t* dst = (sect == 0) ? Q : Kk;
#pragma unroll
                for (int r = 0; r < 4; r++) {
                    float v = acc[i][j][r];
                    float vp = __shfl_xor(v, 1);
                    int s = srow2 + r;
                    float c = fre[s * NP + p], si = fim[s * NP + p];
                    float out = odd ? (vp * si + v * c) : (v * c - vp * si);
                    if (sect == 0) out *= QK_SCALE;
                    dst[((size_t)bh * NS + s) * DHEAD + d] = f2bf(out);
                }
            }
        }
    }
}

// ---------------- flash attention v4 (round-5 best: LDS DMA + rot-swizzle) ----
#define BQ3 128
#define BKV3 64
#define PPAD 72
#define CHCAP 6
#define NPART_BH 51
#define OPART_SPLIT 224   // partials 0..223 in region A, rest in region B

__global__ __launch_bounds__(256, 2) void flash_attn4(const ushort_t* __restrict__ Q,
                                                      const ushort_t* __restrict__ K,
                                                      const ushort_t* __restrict__ Vt,
                                                      ushort_t* __restrict__ OpA,
                                                      ushort_t* __restrict__ OpB,
                                                      float* __restrict__ ml) {
    __shared__ ushort_t sK[BKV3 * 256];        // 32768 B, [key][d] rot-swizzled
    __shared__ ushort_t sV[DHEAD * 64];        // 32768 B, [d][key] rot-swizzled
    __shared__ ushort_t sP[4][16 * PPAD];      // 9216 B, per-wave, gq-sequential

    int rem = blockIdx.x, qt = 15, nsp;
    for (;;) {
        nsp = (2 * (qt + 1) + CHCAP - 1) / CHCAP;
        if (rem < nsp) break;
        rem -= nsp;
        qt--;
    }
    const int nch = 2 * (qt + 1);
    const int cbeg = rem * CHCAP;
    const int cend = (cbeg + CHCAP < nch) ? cbeg + CHCAP : nch;

    const int h = blockIdx.y, b = blockIdx.z;
    const int t = threadIdx.x, w = t >> 6, l = t & 63;
    const int lc = l & 15, lq = l >> 4;
    const int bh = b * NHEADS + h;
    const size_t base = (size_t)bh * NS * DHEAD;
    const int q0 = qt * BQ3;

    // per-lane invariant staging offsets (rotation amount is j-invariant)
    const int krb = w * 2 + (l >> 5);                          // K row base (+8 per issue)
    const int kck = ((l & 31) - (krb & 7)) & 31;               // logical chunk
    const size_t koff = (size_t)krb * 256 + kck * 8;           // + (kb + j*8)*256
    const int vrb = w * 8 + (l >> 3);                          // V row base (+32 per issue)
    const int vck = ((l & 7) - (vrb & 7)) & 7;
    const size_t voff = (size_t)vrb * NS + vck * 8;            // + kb + j*32*NS
    ushort_t* dK = &sK[w * 512 + l * 8];                       // + j*2048
    ushort_t* dV = &sV[w * 512 + l * 8];

    // Q fragments: wave w owns rows [q0+w*32, +32), two 16-row groups
    bf16x8 qf[2][8];
#pragma unroll
    for (int gq = 0; gq < 2; gq++) {
        const ushort_t* qrow = Q + base + (size_t)(q0 + w * 32 + gq * 16 + lc) * DHEAD + lq * 8;
#pragma unroll
        for (int dk = 0; dk < 8; dk++) qf[gq][dk] = *(const bf16x8*)(qrow + dk * 32);
    }

    floatx4 accO[2][16];
#pragma unroll
    for (int gq = 0; gq < 2; gq++)
#pragma unroll
        for (int j = 0; j < 16; j++) accO[gq][j] = (floatx4){0.f, 0.f, 0.f, 0.f};
    float lrun[2][4] = {{0.f, 0.f, 0.f, 0.f}, {0.f, 0.f, 0.f, 0.f}};

    for (int kc = cbeg; kc < cend; kc++) {
        const int kb = kc * BKV3;
        __syncthreads();   // prior chunk's LDS reads done
        {
            const ushort_t* ksrc = K + base + (size_t)kb * 256 + koff;
            const ushort_t* vsrc = Vt + base + kb + voff;
#pragma unroll
            for (int j = 0; j < 8; j++)
                gload_lds16(ksrc + j * (8 * 256), dK + j * 2048);
#pragma unroll
            for (int j = 0; j < 8; j++)
                gload_lds16(vsrc + j * (32 * NS), dV + j * 2048);
        }
        __syncthreads();   // DMA drained (vmcnt(0) implied by barrier)

        // S = Q K^T : 8 independent chains; K-frag shared by both q-groups
        floatx4 sfr[2][4];
#pragma unroll
        for (int gq = 0; gq < 2; gq++)
#pragma unroll
            for (int g = 0; g < 4; g++) sfr[gq][g] = (floatx4){0.f, 0.f, 0.f, 0.f};
#pragma unroll
        for (int dk = 0; dk < 8; dk++) {
#pragma unroll
            for (int g = 0; g < 4; g++) {
                int R = g * 16 + lc;
                int phys = (dk * 4 + lq + (R & 7)) & 31;
                bf16x8 bk = *(const bf16x8*)&sK[R * 256 + phys * 8];
                sfr[0][g] = mfma16(qf[0][dk], bk, sfr[0][g]);
                sfr[1][g] = mfma16(qf[1][dk], bk, sfr[1][g]);
            }
        }

        // causal mask only on the two diagonal chunks
        if (kc >= nch - 2) {
#pragma unroll
            for (int gq = 0; gq < 2; gq++)
#pragma unroll
                for (int g = 0; g < 4; g++) {
                    int kg = kb + g * 16 + lc;
                    int qr = q0 + w * 32 + gq * 16 + lq * 4;
#pragma unroll
                    for (int r = 0; r < 4; r++)
                        if (kg > qr + r) sfr[gq][g][r] = -1e30f;
                }
        }

        // gq-sequential: exp -> P(LDS) -> A-frag -> PV
        ushort_t* pw = sP[w];
#pragma unroll
        for (int gq = 0; gq < 2; gq++) {
#pragma unroll
            for (int g = 0; g < 4; g++)
#pragma unroll
                for (int r = 0; r < 4; r++) {
                    float p = __expf(sfr[gq][g][r]);
                    lrun[gq][r] += p;
                    pw[(lq * 4 + r) * PPAD + g * 16 + lc] = f2bf(p);
                }
            bf16x8 ap0 = *(const bf16x8*)&pw[lc * PPAD + lq * 8];
            bf16x8 ap1 = *(const bf16x8*)&pw[lc * PPAD + 32 + lq * 8];
#pragma unroll
            for (int j = 0; j < 16; j++) {
                int D = j * 16 + lc;
                int ph0 = (lq + (D & 7)) & 7;
                int ph1 = (4 + lq + (D & 7)) & 7;
                bf16x8 bv0 = *(const bf16x8*)&sV[D * 64 + ph0 * 8];
                bf16x8 bv1 = *(const bf16x8*)&sV[D * 64 + ph1 * 8];
                accO[gq][j] = mfma16(ap0, bv0, accO[gq][j]);
                accO[gq][j] = mfma16(ap1, bv1, accO[gq][j]);
            }
        }
    }

    // ---- epilogue: unnormalized partial O (bf16) + row sums l ----
    const int pid = bh * NPART_BH + blockIdx.x;
    ushort_t* op = (pid < OPART_SPLIT) ? OpA + (size_t)pid * (128 * 256)
                                       : OpB + (size_t)(pid - OPART_SPLIT) * (128 * 256);
#pragma unroll
    for (int gq = 0; gq < 2; gq++) {
#pragma unroll
        for (int r = 0; r < 4; r++) {
            int row = w * 32 + gq * 16 + lq * 4 + r;
#pragma unroll
            for (int j = 0; j < 16; j++)
                op[row * 256 + j * 16 + lc] = f2bf(accO[gq][j][r]);
            float lv = lrun[gq][r];
#pragma unroll
            for (int off = 1; off < 16; off <<= 1) lv += __shfl_xor(lv, off);
            if (lc == 0) ml[(size_t)pid * 128 + row] = lv;
        }
    }
}

// ---------------- combine partials: fully parallel, vectorized ----------------
__global__ __launch_bounds__(256) void combine_parts2(const ushort_t* __restrict__ OpA,
                                                      const ushort_t* __restrict__ OpB,
                                                      const float* __restrict__ ml,
                                                      ushort_t* __restrict__ O) {
    const int qt = blockIdx.x >> 3, rsub = blockIdx.x & 7;
    const int h = blockIdx.y, b = blockIdx.z;
    const int bh = b * NHEADS + h;
    int bbase = 0;
    for (int q = 15; q > qt; q--) bbase += (2 * (q + 1) + CHCAP - 1) / CHCAP;
    const int nsp = (2 * (qt + 1) + CHCAP - 1) / CHCAP;
    const int pid0 = bh * NPART_BH + bbase;

    const int t = threadIdx.x;
    const int rl = t >> 4;               // 0..15 local row
    const int c0 = (t & 15) * 16;        // col base
    const int row = rsub * 16 + rl;      // row within 128-row q-tile

    float so[16];
#pragma unroll
    for (int k = 0; k < 16; k++) so[k] = 0.f;
    float sl = 0.f;

    for (int i = 0; i < nsp; i++) {
        int pid = pid0 + i;
        const ushort_t* op = (pid < OPART_SPLIT)
                                 ? OpA + (size_t)pid * (128 * 256)
                                 : OpB + (size_t)(pid - OPART_SPLIT) * (128 * 256);
        const ushort_t* p = op + row * 256 + c0;
        ushortx8 a0 = *(const ushortx8*)p;
        ushortx8 a1 = *(const ushortx8*)(p + 8);
#pragma unroll
        for (int k = 0; k < 8; k++) {
            so[k] += bf2f(a0[k]);
            so[8 + k] += bf2f(a1[k]);
        }
        sl += ml[(size_t)pid * 128 + row];
    }

    float inv = 1.f / sl;
    ushortx8 o0, o1;
#pragma unroll
    for (int k = 0; k < 8; k++) {
        o0[k] = f2bf(so[k] * inv);
        o1[k] = f2bf(so[8 + k] * inv);
    }
    int s = qt * BQ3 + row;
    ushort_t* dst = O + ((size_t)(b * NS + s) * NHEADS + h) * DHEAD + c0;
    *(ushortx8*)dst = o0;
    *(ushortx8*)(dst + 8) = o1;
}

// ---------------- launch ----------------
extern "C" void kernel_launch(void* const* d_in, const int* in_sizes, int n_in,
                              void* d_out, int out_size, void* d_ws, size_t ws_size,
                              hipStream_t stream) {
    const float* hidden = (const float*)d_in[0];
    const float* fre = (const float*)d_in[1];
    const float* fim = (const float*)d_in[2];
    // d_in[3] = mask (causal, reproduced analytically)
    const float* Wqkv = (const float*)d_in[4];
    const float* Wo = (const float*)d_in[5];

    char* ws = (char*)d_ws;
    ushort_t* hb    = (ushort_t*)(ws);                 // [0,8M)   dead after gemm_qkv
    ushort_t* wqkvb = (ushort_t*)(ws + 8388608);       // [8,14M)  dead after gemm_qkv
    ushort_t* wob   = (ushort_t*)(ws + 14680064);      // [14,16M) live till gemm2
    ushort_t* qb    = (ushort_t*)(ws + 16777216);      // [16,24M) dead after flash
    ushort_t* kb    = (ushort_t*)(ws + 25165824);      // [24,32M) dead after flash
    ushort_t* vtb   = (ushort_t*)(ws + 33554432);      // [32,40M) dead after flash
    ushort_t* OpA   = (ushort_t*)(ws);                 // [0,14M)  224 partials (over hb+wqkvb)
    ushort_t* OpB   = (ushort_t*)(ws + 41943040);      // [40M,+11.5M) 184 partials, dead after combine
    ushort_t* oattn = (ushort_t*)(ws + 16777216);      // over dead qb, live till gemm2
    float*    gP0   = (float*)(ws + 25165824);         // [24,40M) over dead kb+vtb
    float*    gP1   = (float*)(ws + 41943040);         // [40,56M) over dead OpB
    float*    ml    = (float*)(ws + 58720256);         // [56M, +209K)

    cast3_kernel<<<(N4_H + N4_WQ + N4_WO) / 256, 256, 0, stream>>>(hidden, Wqkv, Wo, hb);

    gemm_qkv<<<dim3(3072 / 128, 4096 / 128), 256, 0, stream>>>(
        hb, wqkvb, fre, fim, qb, kb, vtb);

    flash_attn4<<<dim3(NPART_BH, NHEADS, NB), 256, 0, stream>>>(qb, kb, vtb, OpA, OpB, ml);
    combine_parts2<<<dim3(128, NHEADS, NB), 256, 0, stream>>>(OpA, OpB, ml, oattn);

    gemm_bt_f32s<<<dim3(1024 / 128, 4096 / 128, 2), 256, 0, stream>>>(
        oattn, wob, gP0, gP1, 4096, 1024, 1024);
    add_f32<<<4096, 256, 0, stream>>>(gP0, gP1, (float*)d_out, 4096 * 1024 / 4);
}